// Round 10
// baseline (4140.930 us; speedup 1.0000x reference)
//
#include <hip/hip_runtime.h>
#include <stdint.h>

#define B_    256
#define T_    1024
#define H_    512
#define NIN_  64
#define NOUT_ 64

// rnn_scan: 64 blocks x 8 waves (2 waves/SIMD, 256 unified regs/wave).
// Wave owns 64 cols (jt 0..3). W per wave:
//   kb 0..7  : AGPR via asm MFMA "a" operands (32 units = 128 AGPRs)
//   kb 8..15 : streamed from L2 every step (32 units, 4 rotating 4-unit bufs)
// LDS holds ONLY the double-buffered tanh(h) A-frags (8.4 KB) -> the LDS
// pipe serves ~128 b128-reads/step instead of R9's 256 (the measured limit).
#define SC_NW   8
#define BBLK    4
#define HROW    528      // hbuf row stride in shorts (1056B -> 8-bank shift/row)
#define KB_AG   8
#define KB_ST   8        // kb 8..15 streamed from L2
#define SW_CHUNKS (SC_NW * KB_ST * 4 * 64)     // 16384 chunks of 16B = 256 KB

typedef __attribute__((ext_vector_type(8))) short bf16x8;
typedef __attribute__((ext_vector_type(4))) float f32x4;

__device__ __forceinline__ short f2bf(float f) {
  uint32_t u = __float_as_uint(f);
  uint32_t r = (u + 0x7FFFu + ((u >> 16) & 1u)) >> 16;
  return (short)(r & 0xFFFFu);
}

__device__ __forceinline__ bf16x8 pack8(float4 lo, float4 hi) {
  bf16x8 s;
  s[0] = f2bf(lo.x); s[1] = f2bf(lo.y); s[2] = f2bf(lo.z); s[3] = f2bf(lo.w);
  s[4] = f2bf(hi.x); s[5] = f2bf(hi.y); s[6] = f2bf(hi.z); s[7] = f2bf(hi.w);
  return s;
}

__device__ __forceinline__ float fast_tanh(float x) {
  float e = __expf(2.0f * x);
  return 1.0f - __fdividef(2.0f, e + 1.0f);
}

// 4 MFMAs (shared A, B pinned in AGPR) in ONE asm block (proven R9).
// Trailing s_nop 7 closes the WAR window on the shared A VGPRs.
__device__ __forceinline__ void mfma4_agpr(
    f32x4& d0, f32x4& d1, f32x4& d2, f32x4& d3, bf16x8 a,
    const bf16x8& b0, const bf16x8& b1, const bf16x8& b2, const bf16x8& b3) {
  asm volatile(
      "v_mfma_f32_16x16x32_bf16 %0, %4, %5, %0\n\t"
      "v_mfma_f32_16x16x32_bf16 %1, %4, %6, %1\n\t"
      "v_mfma_f32_16x16x32_bf16 %2, %4, %7, %2\n\t"
      "v_mfma_f32_16x16x32_bf16 %3, %4, %8, %3\n\t"
      "s_nop 7"
      : "+v"(d0), "+v"(d1), "+v"(d2), "+v"(d3)
      : "v"(a), "a"(b0), "a"(b1), "a"(b2), "a"(b3));
}

// ---------------------------------------------------------------------------
// wprep: pre-convert streamed W (kb 8..15) into per-lane bf16 fragment order.
// chunk c = ((w*8+G)*4 + jt)*64 + lane  ->  16 bytes at sw[c*8].
// ---------------------------------------------------------------------------
__global__ __launch_bounds__(512) void wprep(
    const float* __restrict__ W, short* __restrict__ sw)
{
  const int c = blockIdx.x * 512 + threadIdx.x;
  if (c >= SW_CHUNKS) return;
  const int lane = c & 63;
  const int u    = c >> 6;         // (w*8+G)*4 + jt
  const int jt   = u & 3;
  const int gw   = u >> 2;         // w*8 + G
  const int G    = gw & 7;
  const int w    = gw >> 3;
  const int col  = 64 * w + 16 * jt + (lane & 15);
  const int k0   = 32 * (KB_AG + G) + (lane >> 4) * 8;
  const float4* p = reinterpret_cast<const float4*>(W + (size_t)col * H_ + k0);
  *reinterpret_cast<bf16x8*>(sw + (size_t)c * 8) = pack8(p[0], p[1]);
}

// ---------------------------------------------------------------------------
// xproj: inp[b,t,h] = X[b,t,:] @ Win[h,:]  (f32, written into hid region)
// ---------------------------------------------------------------------------
#define XP_BLOCKS 512
__global__ __launch_bounds__(512, 2) void xproj(
    const float* __restrict__ X, const float* __restrict__ Win,
    float* __restrict__ inp)
{
  const int tid  = threadIdx.x;
  const int lane = tid & 63;
  const int w    = tid >> 6;
  const int g    = lane >> 4;
  const int m    = lane & 15;

  bf16x8 Bf[2][4];
#pragma unroll
  for (int kb = 0; kb < 2; ++kb)
#pragma unroll
    for (int jt = 0; jt < 4; ++jt) {
      const int j = 64 * w + 16 * jt + m;
      const float4* p = reinterpret_cast<const float4*>(Win + (size_t)j * NIN_ + 32 * kb + 8 * g);
      Bf[kb][jt] = pack8(p[0], p[1]);
    }

  const int NTILES = (B_ * T_) / 16;
  const f32x4 zero = {0.f, 0.f, 0.f, 0.f};

  for (int tile = blockIdx.x; tile < NTILES; tile += XP_BLOCKS) {
    const size_t row0 = (size_t)tile * 16;
    f32x4 acc[4];
    {
      const float4* p = reinterpret_cast<const float4*>(X + (row0 + m) * NIN_ + 8 * g);
      const bf16x8 a = pack8(p[0], p[1]);
#pragma unroll
      for (int jt = 0; jt < 4; ++jt)
        acc[jt] = __builtin_amdgcn_mfma_f32_16x16x32_bf16(a, Bf[0][jt], zero, 0, 0, 0);
    }
    {
      const float4* p = reinterpret_cast<const float4*>(X + (row0 + m) * NIN_ + 32 + 8 * g);
      const bf16x8 a = pack8(p[0], p[1]);
#pragma unroll
      for (int jt = 0; jt < 4; ++jt)
        acc[jt] = __builtin_amdgcn_mfma_f32_16x16x32_bf16(a, Bf[1][jt], acc[jt], 0, 0, 0);
    }
#pragma unroll
    for (int jt = 0; jt < 4; ++jt)
#pragma unroll
      for (int r = 0; r < 4; ++r)
        inp[(row0 + 4 * g + r) * H_ + 64 * w + 16 * jt + m] = acc[jt][r];
  }
}

// ---------------------------------------------------------------------------
// rnn_scan
// ---------------------------------------------------------------------------
__global__
__attribute__((amdgpu_flat_work_group_size(512, 512), amdgpu_waves_per_eu(2, 2)))
void rnn_scan(
    const float* __restrict__ h0, const float* __restrict__ W,
    float* __restrict__ hid, const short* __restrict__ swbuf)
{
  __shared__ __align__(16) short hbuf[2][BBLK][HROW];   // 8.4 KB (ALL the LDS)

  const int tid  = threadIdx.x;
  const int lane = tid & 63;
  const int w    = tid >> 6;    // wave 0..7
  const int g    = lane >> 4;
  const int m    = lane & 15;
  const int b0   = blockIdx.x * BBLK;

  // launder pointers: loads from these can't be rematerialized
  const float* Wo = W;
  asm volatile("" : "+s"(Wo));
  const short* SWb = swbuf;
  asm volatile("" : "+s"(SWb));

  // --- AGPR-resident W: kb 0..7 (B[k][col] = W[col][k]); pinned by asm "a" use
  bf16x8 Wa[KB_AG][4];
#pragma unroll
  for (int kb = 0; kb < KB_AG; ++kb)
#pragma unroll
    for (int jt = 0; jt < 4; ++jt) {
      const int col = 64 * w + 16 * jt + m;
      const float4* p = reinterpret_cast<const float4*>(Wo + (size_t)col * H_ + 32 * kb + 8 * g);
      Wa[kb][jt] = pack8(p[0], p[1]);
    }

  // --- hbuf[0] = tanh(h0)
  for (int e = tid; e < BBLK * H_; e += SC_NW * 64) {
    const int r = e >> 9, k = e & (H_ - 1);
    hbuf[0][r][k] = f2bf(fast_tanh(h0[(size_t)(b0 + r) * H_ + k]));
  }

  // --- inp_cur for t=0: lane owns col = 64w+16g+m, rows 0..3
  const int mycol = 64 * w + 16 * g + m;
  float inp_cur[4];
#pragma unroll
  for (int r = 0; r < 4; ++r)
    inp_cur[r] = hid[((size_t)(b0 + r) * T_ + 0) * H_ + mycol];

  // --- stream: groups G0..G7 = kb 8..15, FOUR rotating buffers
  const int sbase = w * (KB_ST * 4 * 64) + lane;   // + (G*4+jt)*64
  const bf16x8* SW = reinterpret_cast<const bf16x8*>(SWb);
  bf16x8 sb0[4], sb1[4], sb2[4], sb3[4];
#pragma unroll
  for (int jt = 0; jt < 4; ++jt) sb0[jt] = SW[sbase + (0 * 4 + jt) * 64];
#pragma unroll
  for (int jt = 0; jt < 4; ++jt) sb1[jt] = SW[sbase + (1 * 4 + jt) * 64];
#pragma unroll
  for (int jt = 0; jt < 4; ++jt) sb2[jt] = SW[sbase + (2 * 4 + jt) * 64];
#pragma unroll
  for (int jt = 0; jt < 4; ++jt) sb3[jt] = SW[sbase + (3 * 4 + jt) * 64];

  __syncthreads();

#pragma clang loop unroll(disable)
  for (int t = 0; t < T_; ++t) {
    const int cur = t & 1, nxt = cur ^ 1;

    // fresh opaque stream base each iteration (blocks CSE across steps)
    uintptr_t swo_u = (uintptr_t)SW;
    asm volatile("" : "+s"(swo_u));
    const bf16x8* SWo = (const bf16x8*)swo_u;

    // inp prefetch for t+1 (overlaps the whole MFMA phase)
    float inp_nxt[4] = {0.f, 0.f, 0.f, 0.f};
    if (t + 1 < T_) {
#pragma unroll
      for (int r = 0; r < 4; ++r)
        inp_nxt[r] = hid[((size_t)(b0 + r) * T_ + (t + 1)) * H_ + mycol];
    }

    const short* hr = &hbuf[cur][m & 3][0];
    f32x4 acc[4];

    // S0: kb8 consume sb0 (builtin, C=0 init); reload sb0 <- G4 (kb12)
    {
      const bf16x8 a = *reinterpret_cast<const bf16x8*>(hr + 32 * 8 + 8 * g);
      const f32x4 zero = {0.f, 0.f, 0.f, 0.f};
#pragma unroll
      for (int jt = 0; jt < 4; ++jt)
        acc[jt] = __builtin_amdgcn_mfma_f32_16x16x32_bf16(a, sb0[jt], zero, 0, 0, 0);
#pragma unroll
      for (int jt = 0; jt < 4; ++jt) sb0[jt] = SWo[sbase + (4 * 4 + jt) * 64];
    }
    // ASM kb0, kb1
#pragma unroll
    for (int kb = 0; kb < 2; ++kb) {
      const bf16x8 a = *reinterpret_cast<const bf16x8*>(hr + 32 * kb + 8 * g);
      mfma4_agpr(acc[0], acc[1], acc[2], acc[3], a,
                 Wa[kb][0], Wa[kb][1], Wa[kb][2], Wa[kb][3]);
    }
    // S1: kb9 consume sb1; reload sb1 <- G5 (kb13)
    {
      const bf16x8 a = *reinterpret_cast<const bf16x8*>(hr + 32 * 9 + 8 * g);
#pragma unroll
      for (int jt = 0; jt < 4; ++jt)
        acc[jt] = __builtin_amdgcn_mfma_f32_16x16x32_bf16(a, sb1[jt], acc[jt], 0, 0, 0);
#pragma unroll
      for (int jt = 0; jt < 4; ++jt) sb1[jt] = SWo[sbase + (5 * 4 + jt) * 64];
    }
    // ASM kb2, kb3
#pragma unroll
    for (int kb = 2; kb < 4; ++kb) {
      const bf16x8 a = *reinterpret_cast<const bf16x8*>(hr + 32 * kb + 8 * g);
      mfma4_agpr(acc[0], acc[1], acc[2], acc[3], a,
                 Wa[kb][0], Wa[kb][1], Wa[kb][2], Wa[kb][3]);
    }
    // S2: kb10 consume sb2; reload sb2 <- G6 (kb14)
    {
      const bf16x8 a = *reinterpret_cast<const bf16x8*>(hr + 32 * 10 + 8 * g);
#pragma unroll
      for (int jt = 0; jt < 4; ++jt)
        acc[jt] = __builtin_amdgcn_mfma_f32_16x16x32_bf16(a, sb2[jt], acc[jt], 0, 0, 0);
#pragma unroll
      for (int jt = 0; jt < 4; ++jt) sb2[jt] = SWo[sbase + (6 * 4 + jt) * 64];
    }
    // ASM kb4, kb5
#pragma unroll
    for (int kb = 4; kb < 6; ++kb) {
      const bf16x8 a = *reinterpret_cast<const bf16x8*>(hr + 32 * kb + 8 * g);
      mfma4_agpr(acc[0], acc[1], acc[2], acc[3], a,
                 Wa[kb][0], Wa[kb][1], Wa[kb][2], Wa[kb][3]);
    }
    // S3: kb11 consume sb3; reload sb3 <- G7 (kb15)
    {
      const bf16x8 a = *reinterpret_cast<const bf16x8*>(hr + 32 * 11 + 8 * g);
#pragma unroll
      for (int jt = 0; jt < 4; ++jt)
        acc[jt] = __builtin_amdgcn_mfma_f32_16x16x32_bf16(a, sb3[jt], acc[jt], 0, 0, 0);
#pragma unroll
      for (int jt = 0; jt < 4; ++jt) sb3[jt] = SWo[sbase + (7 * 4 + jt) * 64];
    }
    // ASM kb6, kb7
#pragma unroll
    for (int kb = 6; kb < 8; ++kb) {
      const bf16x8 a = *reinterpret_cast<const bf16x8*>(hr + 32 * kb + 8 * g);
      mfma4_agpr(acc[0], acc[1], acc[2], acc[3], a,
                 Wa[kb][0], Wa[kb][1], Wa[kb][2], Wa[kb][3]);
    }
    // S4: kb12 consume sb0; reload sb0 <- G0 (next step kb8)
    {
      const bf16x8 a = *reinterpret_cast<const bf16x8*>(hr + 32 * 12 + 8 * g);
#pragma unroll
      for (int jt = 0; jt < 4; ++jt)
        acc[jt] = __builtin_amdgcn_mfma_f32_16x16x32_bf16(a, sb0[jt], acc[jt], 0, 0, 0);
#pragma unroll
      for (int jt = 0; jt < 4; ++jt) sb0[jt] = SWo[sbase + (0 * 4 + jt) * 64];
    }
    // S5: kb13 consume sb1; reload sb1 <- G1
    {
      const bf16x8 a = *reinterpret_cast<const bf16x8*>(hr + 32 * 13 + 8 * g);
#pragma unroll
      for (int jt = 0; jt < 4; ++jt)
        acc[jt] = __builtin_amdgcn_mfma_f32_16x16x32_bf16(a, sb1[jt], acc[jt], 0, 0, 0);
#pragma unroll
      for (int jt = 0; jt < 4; ++jt) sb1[jt] = SWo[sbase + (1 * 4 + jt) * 64];
    }
    // S6: kb14 consume sb2; reload sb2 <- G2
    {
      const bf16x8 a = *reinterpret_cast<const bf16x8*>(hr + 32 * 14 + 8 * g);
#pragma unroll
      for (int jt = 0; jt < 4; ++jt)
        acc[jt] = __builtin_amdgcn_mfma_f32_16x16x32_bf16(a, sb2[jt], acc[jt], 0, 0, 0);
#pragma unroll
      for (int jt = 0; jt < 4; ++jt) sb2[jt] = SWo[sbase + (2 * 4 + jt) * 64];
    }
    // S7: kb15 consume sb3 (LAST acc writer); reload sb3 <- G3
    {
      const bf16x8 a = *reinterpret_cast<const bf16x8*>(hr + 32 * 15 + 8 * g);
#pragma unroll
      for (int jt = 0; jt < 4; ++jt)
        acc[jt] = __builtin_amdgcn_mfma_f32_16x16x32_bf16(a, sb3[jt], acc[jt], 0, 0, 0);
#pragma unroll
      for (int jt = 0; jt < 4; ++jt) sb3[jt] = SWo[sbase + (3 * 4 + jt) * 64];
    }

    // epilogue: lane picks acc[jt=g]; rows r=0..3, col = mycol
#pragma unroll
    for (int r = 0; r < 4; ++r) {
      float v = acc[0][r];
      v = (g == 1) ? acc[1][r] : v;
      v = (g == 2) ? acc[2][r] : v;
      v = (g == 3) ? acc[3][r] : v;
      v += inp_cur[r];
      hid[((size_t)(b0 + r) * T_ + t) * H_ + mycol] = v;
      hbuf[nxt][r][mycol] = f2bf(fast_tanh(v));
    }
#pragma unroll
    for (int r = 0; r < 4; ++r) inp_cur[r] = inp_nxt[r];

    // drain LDS only; vmcnt stays in flight (hid stores, inp/stream loads)
    asm volatile("s_waitcnt lgkmcnt(0)" ::: "memory");
    __builtin_amdgcn_s_barrier();
    asm volatile("" ::: "memory");
  }
}

// ---------------------------------------------------------------------------
// out = hidden @ W_out^T : memory-bound [BT,512]x[512,64] MFMA GEMM.
// ---------------------------------------------------------------------------
#define OP_BLOCKS 1024
#define OP_WAVES  8
__global__ __launch_bounds__(OP_WAVES * 64, 2) void out_proj(
    const float* __restrict__ hid, const float* __restrict__ Wout,
    float* __restrict__ out)
{
  __shared__ __align__(16) short ws[16][NOUT_][32];   // 64 KB

  const int tid  = threadIdx.x;
  const int lane = tid & 63;
  const int w    = tid >> 6;
  const int g    = lane >> 4;
  const int m    = lane & 15;

#pragma unroll
  for (int i = 0; i < 8; ++i) {
    const int c   = tid + OP_WAVES * 64 * i;
    const int kb  = c >> 8;
    const int col = (c >> 2) & 63;
    const int q   = (c & 3) * 8;
    const float4* p = reinterpret_cast<const float4*>(Wout + (size_t)col * H_ + 32 * kb + q);
    *reinterpret_cast<bf16x8*>(&ws[kb][col][q]) = pack8(p[0], p[1]);
  }
  __syncthreads();

  const int wave_id = blockIdx.x * OP_WAVES + w;
  const int NWAVES  = OP_BLOCKS * OP_WAVES;
  const int NTILES  = (B_ * T_) / 16;

  for (int tile = wave_id; tile < NTILES; tile += NWAVES) {
    const size_t row0 = (size_t)tile * 16;
    f32x4 acc[4];
    {
      const float4* p = reinterpret_cast<const float4*>(hid + (row0 + m) * H_ + 8 * g);
      const bf16x8 a = pack8(p[0], p[1]);
      const f32x4 zero = {0.f, 0.f, 0.f, 0.f};
#pragma unroll
      for (int jt = 0; jt < 4; ++jt) {
        const bf16x8 b = *reinterpret_cast<const bf16x8*>(&ws[0][16 * jt + m][8 * g]);
        acc[jt] = __builtin_amdgcn_mfma_f32_16x16x32_bf16(a, b, zero, 0, 0, 0);
      }
    }
#pragma unroll
    for (int kb = 1; kb < 16; ++kb) {
      const float4* p = reinterpret_cast<const float4*>(hid + (row0 + m) * H_ + 32 * kb + 8 * g);
      const bf16x8 a = pack8(p[0], p[1]);
#pragma unroll
      for (int jt = 0; jt < 4; ++jt) {
        const bf16x8 b = *reinterpret_cast<const bf16x8*>(&ws[kb][16 * jt + m][8 * g]);
        acc[jt] = __builtin_amdgcn_mfma_f32_16x16x32_bf16(a, b, acc[jt], 0, 0, 0);
      }
    }
#pragma unroll
    for (int jt = 0; jt < 4; ++jt)
#pragma unroll
      for (int r = 0; r < 4; ++r)
        out[(row0 + 4 * g + r) * NOUT_ + 16 * jt + m] = acc[jt][r];
  }
}

extern "C" void kernel_launch(void* const* d_in, const int* in_sizes, int n_in,
                              void* d_out, int out_size, void* d_ws, size_t ws_size,
                              hipStream_t stream) {
  const float* X    = (const float*)d_in[0];
  const float* h0   = (const float*)d_in[1];
  const float* W    = (const float*)d_in[2];
  const float* Win  = (const float*)d_in[3];
  const float* Wout = (const float*)d_in[4];

  float* out = (float*)d_out;                                   // [B,T,64]
  float* hid = (float*)d_out + (size_t)B_ * T_ * NOUT_;         // [B,T,512] (inp, then h)

  // streamed-W scratch (256 KB) at the tail of the out region; out_proj
  // overwrites it afterwards, so this is scratch-safe within one launch.
  const size_t out_elems = (size_t)B_ * T_ * NOUT_;
  short* sw = (short*)((float*)d_out + out_elems) - (size_t)SW_CHUNKS * 8;

  wprep<<<dim3(SW_CHUNKS / 512), dim3(512), 0, stream>>>(W, sw);
  xproj<<<dim3(XP_BLOCKS), dim3(512), 0, stream>>>(X, Win, hid);
  rnn_scan<<<dim3(B_ / BBLK), dim3(SC_NW * 64), 0, stream>>>(h0, W, hid, sw);
  out_proj<<<dim3(OP_BLOCKS), dim3(OP_WAVES * 64), 0, stream>>>(hid, Wout, out);
}